// Round 1
// baseline (937.757 us; speedup 1.0000x reference)
//
#include <hip/hip_runtime.h>
#include <hip/hip_bf16.h>

using short8  = __attribute__((ext_vector_type(8))) short;
using float4v = __attribute__((ext_vector_type(4))) float;

#define MFMA(a,b,cc) __builtin_amdgcn_mfma_f32_16x16x32_bf16((a),(b),(cc),0,0,0)

__device__ __forceinline__ float fexp(float x){ return __builtin_amdgcn_exp2f(x * 1.44269504088896340736f); }
__device__ __forceinline__ float frcp(float x){ return __builtin_amdgcn_rcpf(x); }

__device__ __forceinline__ short f2bf(float f){
  __hip_bfloat16 h = __float2bfloat16(f);
  return __builtin_bit_cast(short, h);
}

__device__ __forceinline__ short8 load_bf8(const float* p){
  short8 v;
#pragma unroll
  for (int j = 0; j < 8; ++j) v[j] = f2bf(p[j]);
  return v;
}

// Fused 2-layer LSTM + FC head.
// Grid: 64 blocks (16 batch rows each), 512 threads (8 waves).
// Wave w owns gate columns of the PERMUTED weight matrix:
//   if-tile w   : col c -> unit u = 8w + (c>>1), type (c&1 ? f : i)
//   go-tile w+8 : col c -> unit u = 8w + (c>>1), type (c&1 ? o : g)
// so after MFMA, even lanes hold (i,g) and odd lanes hold (f,o) for the same unit.
__global__ __launch_bounds__(512, 2) void lstm2_fused(
    const float* __restrict__ x,     // (1024, 512, 128)
    const float* __restrict__ Wih0,  // (256,128)
    const float* __restrict__ Whh0,  // (256,64)
    const float* __restrict__ bih0, const float* __restrict__ bhh0,
    const float* __restrict__ Wih1,  // (256,64)
    const float* __restrict__ Whh1,  // (256,64)
    const float* __restrict__ bih1, const float* __restrict__ bhh1,
    const float* __restrict__ fcw,   // (64)
    const float* __restrict__ fcb,   // (1)
    float* __restrict__ out)         // (1024)
{
  constexpr int T = 512, DIN = 128;
  const int tid  = threadIdx.x;
  const int lane = tid & 63;
  const int wv   = tid >> 6;    // 0..7
  const int c    = lane & 15;   // column within 16-wide tile
  const int kg   = lane >> 4;   // 0..3 k-group
  const bool odd = (lane & 1);
  const int bstart = blockIdx.x << 4;

  __shared__ __align__(16) __hip_bfloat16 h0s[16][72];  // +8 pad breaks bank conflicts
  __shared__ __align__(16) __hip_bfloat16 h1s[16][72];
  __shared__ float hfin[16][64];

  const int u   = (wv << 3) + (c >> 1);
  const int rif = ((c & 1) << 6) + u;        // original row: i (even) / f (odd)
  const int rgo = 128 + rif;                 // original row: g (even) / o (odd)

  // ---- load weight B-fragments (once) ----
  short8 wih0f[4], wih0g[4];
#pragma unroll
  for (int kk = 0; kk < 4; ++kk){
    wih0f[kk] = load_bf8(Wih0 + rif*128 + kk*32 + kg*8);
    wih0g[kk] = load_bf8(Wih0 + rgo*128 + kk*32 + kg*8);
  }
  short8 whh0f[2], whh0g[2], wih1f[2], wih1g[2], whh1f[2], whh1g[2];
#pragma unroll
  for (int kk = 0; kk < 2; ++kk){
    const int k0 = kk*32 + kg*8;
    whh0f[kk] = load_bf8(Whh0 + rif*64 + k0);
    whh0g[kk] = load_bf8(Whh0 + rgo*64 + k0);
    wih1f[kk] = load_bf8(Wih1 + rif*64 + k0);
    wih1g[kk] = load_bf8(Wih1 + rgo*64 + k0);
    whh1f[kk] = load_bf8(Whh1 + rif*64 + k0);
    whh1g[kk] = load_bf8(Whh1 + rgo*64 + k0);
  }
  const float bif0 = bih0[rif] + bhh0[rif];
  const float bgo0 = bih0[rgo] + bhh0[rgo];
  const float bif1 = bih1[rif] + bhh1[rif];
  const float bgo1 = bih1[rgo] + bhh1[rgo];

  // ---- state ----
  float4v c0 = {0.f,0.f,0.f,0.f}, c1 = {0.f,0.f,0.f,0.f};
  short8 zer; 
#pragma unroll
  for (int j = 0; j < 8; ++j) zer[j] = 0;
  short8 hf0[2] = {zer, zer}, hf1[2] = {zer, zer};

  // x A-fragment source: lane -> batch row c, dims kg*8 + 32*kk + [0..8)
  const float* xrow = x + (size_t)(bstart + c) * T * DIN + kg*8;
  float4v xr[4][2];
#pragma unroll
  for (int kk = 0; kk < 4; ++kk){
    xr[kk][0] = *(const float4v*)(xrow + kk*32);
    xr[kk][1] = *(const float4v*)(xrow + kk*32 + 4);
  }

  for (int t = 0; t < T; ++t){
    // ================= layer 0 =================
    float4v aif = {bif0, bif0, bif0, bif0};
    float4v ago = {bgo0, bgo0, bgo0, bgo0};
    // recurrent part (h0_{t-1})
    aif = MFMA(hf0[0], whh0f[0], aif);
    aif = MFMA(hf0[1], whh0f[1], aif);
    ago = MFMA(hf0[0], whh0g[0], ago);
    ago = MFMA(hf0[1], whh0g[1], ago);

    // convert prefetched x_t -> bf16 frags
    short8 xb[4];
#pragma unroll
    for (int kk = 0; kk < 4; ++kk){
      short8 v;
#pragma unroll
      for (int j = 0; j < 4; ++j){ v[j] = f2bf(xr[kk][0][j]); v[j+4] = f2bf(xr[kk][1][j]); }
      xb[kk] = v;
    }
    // prefetch x_{t+1}
    if (t + 1 < T){
      const float* nx = xrow + (size_t)(t + 1) * DIN;
#pragma unroll
      for (int kk = 0; kk < 4; ++kk){
        xr[kk][0] = *(const float4v*)(nx + kk*32);
        xr[kk][1] = *(const float4v*)(nx + kk*32 + 4);
      }
    }
    // input part
#pragma unroll
    for (int kk = 0; kk < 4; ++kk){
      aif = MFMA(xb[kk], wih0f[kk], aif);
      ago = MFMA(xb[kk], wih0g[kk], ago);
    }
    // gates: even lane has (i,g), odd lane has (f,o) for unit u, 4 batch rows
    {
      float hv[4];
#pragma unroll
      for (int r = 0; r < 4; ++r){
        float sif = frcp(1.f + fexp(-aif[r]));          // sigmoid: i (even) / f (odd)
        float gg  = ago[r];
        float m   = odd ? -gg : 2.f*gg;
        float rr  = frcp(1.f + fexp(m));
        float vgo = odd ? rr : 1.f - 2.f*rr;            // o (odd) / tanh g (even)
        float p   = sif * vgo;                          // even: i*g
        float psh = __shfl_xor(p, 1, 64);               // odd receives i*g
        float cn  = sif * c0[r] + psh;                  // odd: f*c + i*g (valid)
        c0[r] = cn;
        float tc  = 1.f - 2.f*frcp(1.f + fexp(2.f*cn)); // tanh(c)
        hv[r] = vgo * tc;                               // odd: o*tanh(c) (valid)
      }
      if (odd){
#pragma unroll
        for (int r = 0; r < 4; ++r)
          h0s[kg*4 + r][u] = __float2bfloat16(hv[r]);
      }
    }
    __syncthreads();
    hf0[0] = *(const short8*)&h0s[c][kg*8];
    hf0[1] = *(const short8*)&h0s[c][32 + kg*8];

    // ================= layer 1 =================
    float4v aif1 = {bif1, bif1, bif1, bif1};
    float4v ago1 = {bgo1, bgo1, bgo1, bgo1};
    aif1 = MFMA(hf0[0], wih1f[0], aif1);
    aif1 = MFMA(hf0[1], wih1f[1], aif1);
    ago1 = MFMA(hf0[0], wih1g[0], ago1);
    ago1 = MFMA(hf0[1], wih1g[1], ago1);
    aif1 = MFMA(hf1[0], whh1f[0], aif1);
    aif1 = MFMA(hf1[1], whh1f[1], aif1);
    ago1 = MFMA(hf1[0], whh1g[0], ago1);
    ago1 = MFMA(hf1[1], whh1g[1], ago1);
    {
      float hv[4];
#pragma unroll
      for (int r = 0; r < 4; ++r){
        float sif = frcp(1.f + fexp(-aif1[r]));
        float gg  = ago1[r];
        float m   = odd ? -gg : 2.f*gg;
        float rr  = frcp(1.f + fexp(m));
        float vgo = odd ? rr : 1.f - 2.f*rr;
        float p   = sif * vgo;
        float psh = __shfl_xor(p, 1, 64);
        float cn  = sif * c1[r] + psh;
        c1[r] = cn;
        float tc  = 1.f - 2.f*frcp(1.f + fexp(2.f*cn));
        hv[r] = vgo * tc;
      }
      if (odd){
#pragma unroll
        for (int r = 0; r < 4; ++r){
          h1s[kg*4 + r][u] = __float2bfloat16(hv[r]);
          if (t == T - 1) hfin[kg*4 + r][u] = hv[r];
        }
      }
    }
    __syncthreads();
    hf1[0] = *(const short8*)&h1s[c][kg*8];
    hf1[1] = *(const short8*)&h1s[c][32 + kg*8];
  }

  // ---- FC head: out[b] = sigmoid(h1_last . fcw + fcb) ----
  if (tid < 16){
    float s = fcb[0];
#pragma unroll
    for (int k = 0; k < 64; ++k) s += hfin[tid][k] * fcw[k];
    out[bstart + tid] = frcp(1.f + fexp(-s));
  }
}

extern "C" void kernel_launch(void* const* d_in, const int* in_sizes, int n_in,
                              void* d_out, int out_size, void* d_ws, size_t ws_size,
                              hipStream_t stream) {
  const float* x    = (const float*)d_in[0];
  const float* Wih0 = (const float*)d_in[1];
  const float* Whh0 = (const float*)d_in[2];
  const float* bih0 = (const float*)d_in[3];
  const float* bhh0 = (const float*)d_in[4];
  const float* Wih1 = (const float*)d_in[5];
  const float* Whh1 = (const float*)d_in[6];
  const float* bih1 = (const float*)d_in[7];
  const float* bhh1 = (const float*)d_in[8];
  const float* fcw  = (const float*)d_in[9];
  const float* fcb  = (const float*)d_in[10];
  float* out = (float*)d_out;

  hipLaunchKernelGGL(lstm2_fused, dim3(64), dim3(512), 0, stream,
                     x, Wih0, Whh0, bih0, bhh0, Wih1, Whh1, bih1, bhh1, fcw, fcb, out);
}

// Round 2
// 704.670 us; speedup vs baseline: 1.3308x; 1.3308x over previous
//
#include <hip/hip_runtime.h>
#include <hip/hip_bf16.h>

using short8  = __attribute__((ext_vector_type(8))) short;
using float4v = __attribute__((ext_vector_type(4))) float;

#define MFMA(a,b,cc) __builtin_amdgcn_mfma_f32_16x16x32_bf16((a),(b),(cc),0,0,0)

static __device__ __forceinline__ float fexp(float x){ return __builtin_amdgcn_exp2f(x * 1.44269504088896340736f); }
static __device__ __forceinline__ float frcp(float x){ return __builtin_amdgcn_rcpf(x); }

static __device__ __forceinline__ short f2bf(float f){
  __hip_bfloat16 h = __float2bfloat16(f);
  return __builtin_bit_cast(short, h);
}

static __device__ __forceinline__ short8 load_bf8(const float* p){
  short8 v;
#pragma unroll
  for (int j = 0; j < 8; ++j) v[j] = f2bf(p[j]);
  return v;
}

// gate nonlinearity: even lane holds (i, g~), odd lane holds (f, o) for the
// same hidden unit; odd lane ends up with the valid c and h.
static __device__ __forceinline__ void gates(const float4v& aif, const float4v& ago,
                                             bool odd, float cst[4], float hv[4]){
#pragma unroll
  for (int r = 0; r < 4; ++r){
    float sif = frcp(1.f + fexp(-aif[r]));           // sigmoid: i (even) / f (odd)
    float gg  = ago[r];
    float m   = odd ? -gg : 2.f*gg;
    float rr  = frcp(1.f + fexp(m));
    float vgo = odd ? rr : 1.f - 2.f*rr;             // o (odd) / tanh g (even)
    float p   = sif * vgo;                            // even: i*g~
    float psh = __shfl_xor(p, 1, 64);                 // odd receives i*g~
    float cn  = sif * cst[r] + psh;                   // odd: f*c + i*g~
    cst[r] = cn;
    float tc  = 1.f - 2.f*frcp(1.f + fexp(2.f*cn));   // tanh(c)
    hv[r] = vgo * tc;                                 // odd: o*tanh(c)
  }
}

// Fused 2-layer LSTM, layer-pipelined within the block:
// waves 0-3 compute layer0 step t while waves 4-7 compute layer1 step t-1.
// One barrier per iteration; h exchanged via double-buffered LDS.
__global__ __launch_bounds__(512) void lstm2_pipe(
    const float* __restrict__ x,     // (1024, 512, 128)
    const float* __restrict__ Wih0,  // (256,128)
    const float* __restrict__ Whh0,  // (256,64)
    const float* __restrict__ bih0, const float* __restrict__ bhh0,
    const float* __restrict__ Wih1,  // (256,64)
    const float* __restrict__ Whh1,  // (256,64)
    const float* __restrict__ bih1, const float* __restrict__ bhh1,
    const float* __restrict__ fcw,   // (64)
    const float* __restrict__ fcb,   // (1)
    float* __restrict__ out)         // (1024)
{
  constexpr int T = 512, DIN = 128;
  const int tid  = threadIdx.x;
  const int lane = tid & 63;
  const int wv   = tid >> 6;     // 0..7
  const int grp  = wv >> 2;      // 0: layer0 waves, 1: layer1 waves
  const int wl   = wv & 3;       // wave index within group
  const int c    = lane & 15;
  const int kg   = lane >> 4;    // 0..3
  const bool odd = (lane & 1);
  const int bstart = blockIdx.x << 4;

  __shared__ __align__(16) __hip_bfloat16 h0s[2][16][72];  // double-buffered h0
  __shared__ __align__(16) __hip_bfloat16 h1s[2][16][72];  // double-buffered h1
  __shared__ float hfin[16][64];

  // zero the "t = -1" buffers (index 1 is read at it=0 / tt=0)
  {
    __hip_bfloat16 z = __float2bfloat16(0.f);
    for (int i = tid; i < 16*72; i += 512){
      (&h0s[1][0][0])[i] = z;
      (&h1s[1][0][0])[i] = z;
    }
  }

  // wave owns 16 units: p=0 -> units wl*16+0..7, p=1 -> wl*16+8..15
  const int u0   = wl*16 + (c >> 1);
  const int u1   = u0 + 8;
  const int rifA = ((c & 1) << 6) + u0, rgoA = rifA + 128;
  const int rifB = ((c & 1) << 6) + u1, rgoB = rifB + 128;

  short8 wf0[2][4], wg0[2][4];   // group0: W_ih0 fragments [pair][kfrag]
  short8 whf[2][2], whg[2][2];   // group0: W_hh0 / group1: W_hh1
  short8 wif[2][2], wig[2][2];   // group1: W_ih1
  float bif[2], bgo[2];
  float4v xr[4][2];
  const float* xrow = nullptr;

  if (grp == 0){
#pragma unroll
    for (int p = 0; p < 2; ++p){
      const int rif = p ? rifB : rifA, rgo = p ? rgoB : rgoA;
#pragma unroll
      for (int kk = 0; kk < 4; ++kk){
        wf0[p][kk] = load_bf8(Wih0 + rif*128 + kk*32 + kg*8);
        wg0[p][kk] = load_bf8(Wih0 + rgo*128 + kk*32 + kg*8);
      }
#pragma unroll
      for (int kk = 0; kk < 2; ++kk){
        whf[p][kk] = load_bf8(Whh0 + rif*64 + kk*32 + kg*8);
        whg[p][kk] = load_bf8(Whh0 + rgo*64 + kk*32 + kg*8);
      }
      bif[p] = bih0[rif] + bhh0[rif];
      bgo[p] = bih0[rgo] + bhh0[rgo];
    }
    xrow = x + (size_t)(bstart + c) * T * DIN + kg*8;
#pragma unroll
    for (int kk = 0; kk < 4; ++kk){
      xr[kk][0] = *(const float4v*)(xrow + kk*32);
      xr[kk][1] = *(const float4v*)(xrow + kk*32 + 4);
    }
  } else {
#pragma unroll
    for (int p = 0; p < 2; ++p){
      const int rif = p ? rifB : rifA, rgo = p ? rgoB : rgoA;
#pragma unroll
      for (int kk = 0; kk < 2; ++kk){
        wif[p][kk] = load_bf8(Wih1 + rif*64 + kk*32 + kg*8);
        wig[p][kk] = load_bf8(Wih1 + rgo*64 + kk*32 + kg*8);
        whf[p][kk] = load_bf8(Whh1 + rif*64 + kk*32 + kg*8);
        whg[p][kk] = load_bf8(Whh1 + rgo*64 + kk*32 + kg*8);
      }
      bif[p] = bih1[rif] + bhh1[rif];
      bgo[p] = bih1[rgo] + bhh1[rgo];
    }
  }

  float cstA[4] = {0.f,0.f,0.f,0.f};
  float cstB[4] = {0.f,0.f,0.f,0.f};

  __syncthreads();  // covers zero-init

  for (int it = 0; it <= T; ++it){
    if (grp == 0){
      if (it < T){
        // ---- layer 0, step it ----
        short8 xb[4];
#pragma unroll
        for (int kk = 0; kk < 4; ++kk){
          short8 v;
#pragma unroll
          for (int j = 0; j < 4; ++j){ v[j] = f2bf(xr[kk][0][j]); v[j+4] = f2bf(xr[kk][1][j]); }
          xb[kk] = v;
        }
        if (it + 1 < T){
          const float* nx = xrow + (size_t)(it + 1) * DIN;
#pragma unroll
          for (int kk = 0; kk < 4; ++kk){
            xr[kk][0] = *(const float4v*)(nx + kk*32);
            xr[kk][1] = *(const float4v*)(nx + kk*32 + 4);
          }
        }
        float4v aA = {bif[0],bif[0],bif[0],bif[0]};
        float4v gA = {bgo[0],bgo[0],bgo[0],bgo[0]};
        float4v aB = {bif[1],bif[1],bif[1],bif[1]};
        float4v gB = {bgo[1],bgo[1],bgo[1],bgo[1]};
        // input part first (doesn't depend on the barrier'd h)
#pragma unroll
        for (int kk = 0; kk < 4; ++kk){
          aA = MFMA(xb[kk], wf0[0][kk], aA);
          gA = MFMA(xb[kk], wg0[0][kk], gA);
          aB = MFMA(xb[kk], wf0[1][kk], aB);
          gB = MFMA(xb[kk], wg0[1][kk], gB);
        }
        // recurrent part: h0[it-1]
        const int rb = (it - 1) & 1;   // it=0 -> buffer 1 (zeroed)
        short8 hf[2];
        hf[0] = *(const short8*)&h0s[rb][c][kg*8];
        hf[1] = *(const short8*)&h0s[rb][c][32 + kg*8];
#pragma unroll
        for (int kk = 0; kk < 2; ++kk){
          aA = MFMA(hf[kk], whf[0][kk], aA);
          gA = MFMA(hf[kk], whg[0][kk], gA);
          aB = MFMA(hf[kk], whf[1][kk], aB);
          gB = MFMA(hf[kk], whg[1][kk], gB);
        }
        float hvA[4], hvB[4];
        gates(aA, gA, odd, cstA, hvA);
        gates(aB, gB, odd, cstB, hvB);
        if (odd){
          const int wb = it & 1;
#pragma unroll
          for (int r = 0; r < 4; ++r){
            h0s[wb][kg*4 + r][u0] = __float2bfloat16(hvA[r]);
            h0s[wb][kg*4 + r][u1] = __float2bfloat16(hvB[r]);
          }
        }
      }
    } else {
      if (it >= 1){
        // ---- layer 1, step tt = it-1 ----
        const int tt  = it - 1;
        const int rb0 = tt & 1;        // h0[tt]
        const int rb1 = (tt - 1) & 1;  // h1[tt-1]; tt=0 -> buffer 1 (zeroed)
        short8 hf0[2], hf1[2];
        hf0[0] = *(const short8*)&h0s[rb0][c][kg*8];
        hf0[1] = *(const short8*)&h0s[rb0][c][32 + kg*8];
        hf1[0] = *(const short8*)&h1s[rb1][c][kg*8];
        hf1[1] = *(const short8*)&h1s[rb1][c][32 + kg*8];
        float4v aA = {bif[0],bif[0],bif[0],bif[0]};
        float4v gA = {bgo[0],bgo[0],bgo[0],bgo[0]};
        float4v aB = {bif[1],bif[1],bif[1],bif[1]};
        float4v gB = {bgo[1],bgo[1],bgo[1],bgo[1]};
#pragma unroll
        for (int kk = 0; kk < 2; ++kk){
          aA = MFMA(hf0[kk], wif[0][kk], aA);
          gA = MFMA(hf0[kk], wig[0][kk], gA);
          aB = MFMA(hf0[kk], wif[1][kk], aB);
          gB = MFMA(hf0[kk], wig[1][kk], gB);
        }
#pragma unroll
        for (int kk = 0; kk < 2; ++kk){
          aA = MFMA(hf1[kk], whf[0][kk], aA);
          gA = MFMA(hf1[kk], whg[0][kk], gA);
          aB = MFMA(hf1[kk], whf[1][kk], aB);
          gB = MFMA(hf1[kk], whg[1][kk], gB);
        }
        float hvA[4], hvB[4];
        gates(aA, gA, odd, cstA, hvA);
        gates(aB, gB, odd, cstB, hvB);
        if (odd){
          const int wb = tt & 1;
#pragma unroll
          for (int r = 0; r < 4; ++r){
            h1s[wb][kg*4 + r][u0] = __float2bfloat16(hvA[r]);
            h1s[wb][kg*4 + r][u1] = __float2bfloat16(hvB[r]);
          }
          if (tt == T - 1){
#pragma unroll
            for (int r = 0; r < 4; ++r){
              hfin[kg*4 + r][u0] = hvA[r];
              hfin[kg*4 + r][u1] = hvB[r];
            }
          }
        }
      }
    }
    __syncthreads();
  }

  // ---- FC head: out[b] = sigmoid(h1_last . fcw + fcb) ----
  if (tid < 16){
    float s = fcb[0];
#pragma unroll
    for (int k = 0; k < 64; ++k) s += hfin[tid][k] * fcw[k];
    out[bstart + tid] = frcp(1.f + fexp(-s));
  }
}

extern "C" void kernel_launch(void* const* d_in, const int* in_sizes, int n_in,
                              void* d_out, int out_size, void* d_ws, size_t ws_size,
                              hipStream_t stream) {
  const float* x    = (const float*)d_in[0];
  const float* Wih0 = (const float*)d_in[1];
  const float* Whh0 = (const float*)d_in[2];
  const float* bih0 = (const float*)d_in[3];
  const float* bhh0 = (const float*)d_in[4];
  const float* Wih1 = (const float*)d_in[5];
  const float* Whh1 = (const float*)d_in[6];
  const float* bih1 = (const float*)d_in[7];
  const float* bhh1 = (const float*)d_in[8];
  const float* fcw  = (const float*)d_in[9];
  const float* fcb  = (const float*)d_in[10];
  float* out = (float*)d_out;

  hipLaunchKernelGGL(lstm2_pipe, dim3(64), dim3(512), 0, stream,
                     x, Wih0, Whh0, bih0, bhh0, Wih1, Whh1, bih1, bhh1, fcw, fcb, out);
}